// Round 13
// baseline (536.762 us; speedup 1.0000x reference)
//
#include <hip/hip_runtime.h>
#include <stdint.h>

// B=2, S=2048, DIM=4096, NQ=32, NKV=8, HD=128, n_rep=4, start_pos=0 (so the
// caches are fully overwritten: K/V == rope(x@wk), x@wv; cache inputs unused).

typedef __attribute__((ext_vector_type(8))) short short8;
typedef __attribute__((ext_vector_type(4))) float f32x4;
typedef __attribute__((ext_vector_type(16))) float f32x16;

#define DEVFN static __device__ __forceinline__

DEVFN ushort f2bf(float f) {
  uint32_t u = __builtin_bit_cast(uint32_t, f);
  u += 0x7fffu + ((u >> 16) & 1);          // round-to-nearest-even
  return (ushort)(u >> 16);
}

DEVFN void gll16(const void* g, void* l) {  // global -> LDS, 16B/lane
  __builtin_amdgcn_global_load_lds(
      (const __attribute__((address_space(1))) void*)g,
      (__attribute__((address_space(3))) void*)l, 16, 0, 0);
}

DEVFN float xhalf_max(float v) { return fmaxf(v, __shfl_xor(v, 32)); }
DEVFN float xhalf_add(float v) { return v + __shfl_xor(v, 32); }

#if __has_builtin(__builtin_amdgcn_exp2f)
DEVFN float ex2(float x) { return __builtin_amdgcn_exp2f(x); }
#else
DEVFN float ex2(float x) {
  float r;
  asm("v_exp_f32 %0, %1" : "=v"(r) : "v"(x));
  return r;
}
#endif

// packed 2xf32 -> bf16x2, lo=a hi=b (HW-verified operand order, T12/m214v22)
DEVFN uint32_t cvtpk(float a, float b) {
  uint32_t r;
  asm("v_cvt_pk_bf16_f32 %0, %1, %2" : "=v"(r) : "v"(a), "v"(b));
  return r;
}

DEVFN float vmax16(const f32x16& v) {      // max3-fusable tree, depth 3
  float a0 = fmaxf(fmaxf(v[0], v[1]), v[2]);
  float a1 = fmaxf(fmaxf(v[3], v[4]), v[5]);
  float a2 = fmaxf(fmaxf(v[6], v[7]), v[8]);
  float a3 = fmaxf(fmaxf(v[9], v[10]), v[11]);
  float a4 = fmaxf(fmaxf(v[12], v[13]), v[14]);
  float b0 = fmaxf(fmaxf(a0, a1), a2);
  float b1 = fmaxf(fmaxf(a3, a4), v[15]);
  return fmaxf(b0, b1);
}
DEVFN float vsum16(const f32x16& v) {      // pairwise tree, depth 4
  float s0 = (v[0] + v[1]) + (v[2] + v[3]);
  float s1 = (v[4] + v[5]) + (v[6] + v[7]);
  float s2 = (v[8] + v[9]) + (v[10] + v[11]);
  float s3 = (v[12] + v[13]) + (v[14] + v[15]);
  return (s0 + s1) + (s2 + s3);
}

// Build PV A-frag (8 contiguous k per lane) from packed S^T words.
DEVFN short8 mk_frag(uint32_t w0, uint32_t w1, uint32_t w2, uint32_t w3, int hi) {
  uint32_t x0 = __shfl_xor(w0, 32);
  uint32_t x1 = __shfl_xor(w1, 32);
  uint32_t x2 = __shfl_xor(w2, 32);
  uint32_t x3 = __shfl_xor(w3, 32);
  uint4 u;
  u.x = hi ? x2 : w0;
  u.y = hi ? x3 : w1;
  u.z = hi ? w2 : x0;
  u.w = hi ? w3 : x1;
  return __builtin_bit_cast(short8, u);
}

#define VMW(N) asm volatile("s_waitcnt vmcnt(" #N ")" ::: "memory")

// ---------------------------------------------------------------- fp32->bf16
__global__ __launch_bounds__(256) void k_cvt(const float* __restrict__ src,
                                             ushort* __restrict__ dst, int n8) {
  int i = blockIdx.x * 256 + threadIdx.x;
  if (i >= n8) return;
  const float4* s4 = (const float4*)src + (size_t)i * 2;
  float4 a = s4[0], b = s4[1];
  uint4 o;
  o.x = (uint32_t)f2bf(a.x) | ((uint32_t)f2bf(a.y) << 16);
  o.y = (uint32_t)f2bf(a.z) | ((uint32_t)f2bf(a.w) << 16);
  o.z = (uint32_t)f2bf(b.x) | ((uint32_t)f2bf(b.y) << 16);
  o.w = (uint32_t)f2bf(b.z) | ((uint32_t)f2bf(b.w) << 16);
  ((uint4*)dst)[i] = o;
}

// ---------------- transpose + cvt: [R][C]f32 -> [C][R]bf16 (vectorized, G13)
DEVFN void tr_body(const float* __restrict__ src, ushort* __restrict__ dst,
                   int R, int C, int c0, int r0, int t, ushort* tl) {
  const int r = t >> 4, c4 = (t & 15) << 2;
#pragma unroll
  for (int i = 0; i < 4; ++i) {
    const int rr = r + i * 16;
    float4 v = *(const float4*)&src[(size_t)(r0 + rr) * C + c0 + c4];
    ushort bv[4] = {f2bf(v.x), f2bf(v.y), f2bf(v.z), f2bf(v.w)};
#pragma unroll
    for (int j = 0; j < 4; ++j) {
      const int c = c4 + j;
      *(ushort*)((char*)tl + c * 128 + (((rr >> 3) ^ (c & 7)) << 4) +
                 ((rr & 7) << 1)) = bv[j];
    }
  }
  __syncthreads();
  const int cc = t >> 2;
#pragma unroll
  for (int i = 0; i < 2; ++i) {
    const int ch = (t & 3) + i * 4;        // 8-element r-chunk
    short8 v = *(const short8*)((char*)tl + cc * 128 + ((ch ^ (cc & 7)) << 4));
    *(short8*)&dst[(size_t)(c0 + cc) * R + r0 + ch * 8] = v;
  }
}

__global__ __launch_bounds__(256) void k_tr(const float* __restrict__ src,
                                            ushort* __restrict__ dst, int R, int C) {
  __shared__ ushort tl[64 * 64];            // 8KB, elem (c,r) at row c
  tr_body(src, dst, R, C, blockIdx.x * 64, blockIdx.y * 64, threadIdx.x, tl);
}

// merged wq|wk|wv transpose into one launch: grid (96,64).
__global__ __launch_bounds__(256) void k_tr3(const float* __restrict__ wq,
                                             const float* __restrict__ wk,
                                             const float* __restrict__ wv,
                                             ushort* __restrict__ dst) {
  __shared__ ushort tl[64 * 64];
  const int bx = blockIdx.x;
  const float* src;
  ushort* d;
  int C, cb;
  if (bx < 64) { src = wq; d = dst; C = 4096; cb = bx; }
  else if (bx < 80) { src = wk; d = dst + (size_t)4096 * 4096; C = 1024; cb = bx - 64; }
  else { src = wv; d = dst + (size_t)5120 * 4096; C = 1024; cb = bx - 80; }
  tr_body(src, d, 4096, C, cb * 64, blockIdx.y * 64, threadIdx.x, tl);
}

// ------------------------------------- decoupled reg-dbuf pipelined GEMM C=A*B^T
// (R9-proven: ring-4 LDS, per-tile counted VMW(4), reg-double-buffered frags.)
// MODE 0: BN=192, N=6144 (Q|K|V rows 0/4096/5120), 4M x 2N waves, B dbuf,
//         rope epilogue. MODE 1: BN=256, N=4096, 2M x 4N waves, B JIT, f32 C.
template <int MODE>
__global__ __launch_bounds__(512, 2) void k_gemm8(
    const ushort* __restrict__ A, const ushort* __restrict__ Bp,
    const float* __restrict__ fcis, ushort* __restrict__ oQ,
    ushort* __restrict__ oK, ushort* __restrict__ oV, float* __restrict__ oC) {
  constexpr int K = 4096;
  constexpr int BN = MODE ? 256 : 192;
  constexpr int NBX = MODE ? 16 : 32;
  constexpr int ABUF = 16384;            // 256 rows * 64 B
  constexpr int BBUF = BN * 64;          // 16384 / 12288
  constexpr int NT = K / 32;             // 128
  constexpr int WNG = MODE ? 4 : 2;      // wave grid: (8/WNG) x WNG
  constexpr int MF = MODE ? 8 : 4;       // m-frags per wave
  constexpr int NF = MODE ? 4 : 6;       // n-frags per wave
  constexpr int MH = MF / 2;
  constexpr int MSPAN = 16 * MF;         // 128 / 64
  constexpr int NSPAN = 16 * NF;         // 64 / 96

  __shared__ char smem[4 * ABUF + 4 * BBUF];   // 128 / 112 KB
  char* AsL = smem;
  char* BsL = smem + 4 * ABUF;

  constexpr int nwg = NBX * 16;
  const int bid = blockIdx.x;
  const int wg = (bid & 7) * (nwg >> 3) + (bid >> 3);   // XCD swizzle (bijective)
  const int nb = wg % NBX, mb = wg / NBX;
  const int m0 = mb * 256, n0 = nb * BN;

  const int tid = threadIdx.x;
  const int w = tid >> 6, lane = tid & 63;
  const int gg = lane >> 4, rr = lane & 15;
  const int wm = w / WNG, wn = w % WNG;

  // staging: linear LDS dest (gll16), inverse-swizzled global source.
  const int l8 = lane >> 3, s7 = lane & 7;
  const int Ra0 = w * 8 + l8, Ra1 = 64 + Ra0;
  const int ea0 = s7 ^ (Ra0 & 7), ea1 = s7 ^ (Ra1 & 7);
  const ushort* agp0 = A + (size_t)(m0 + 2 * Ra0 + (ea0 >> 2)) * K + (ea0 & 3) * 8;
  const ushort* agp1 = A + (size_t)(m0 + 2 * Ra1 + (ea1 >> 2)) * K + (ea1 & 3) * 8;
  char* lda0 = AsL + w * 1024;
  char* lda1 = AsL + 8192 + w * 1024;

  const int Rb0 = w * 8 + l8;
  const int eb0 = s7 ^ (Rb0 & 7);
  const ushort* bgp0 = Bp + (size_t)(n0 + 2 * Rb0 + (eb0 >> 2)) * K + (eb0 & 3) * 8;
  char* ldb0 = BsL + w * 1024;
  const int Rb1 = MODE ? (64 + w * 8 + l8) : (64 + w * 4 + l8);
  const int eb1 = s7 ^ (Rb1 & 7);
  const ushort* bgp1 = Bp + (size_t)(n0 + 2 * Rb1 + (eb1 >> 2)) * K + (eb1 & 3) * 8;
  char* ldb1 = BsL + 8192 + (MODE ? w * 1024 : w * 512);

  auto STAGE_A = [&](int t) {
    const int bo = t & 3;
    const size_t ko = (size_t)t * 32;
    gll16(agp0 + ko, lda0 + bo * ABUF);
    gll16(agp1 + ko, lda1 + bo * ABUF);
  };
  auto STAGE_B = [&](int t) {
    const int bo = t & 3;
    const size_t ko = (size_t)t * 32;
    gll16(bgp0 + ko, ldb0 + bo * BBUF);
    if constexpr (MODE) {
      gll16(bgp1 + ko, ldb1 + bo * BBUF);
    } else {
      if (lane < 32) gll16(bgp1 + ko, ldb1 + bo * BBUF);
    }
  };

  int aoff[MF], boff[NF];
#pragma unroll
  for (int mf = 0; mf < MF; ++mf) {
    const int m = wm * MSPAN + mf * 16 + rr;
    aoff[mf] = (m >> 1) * 128 + (((((m & 1) << 2) | gg) ^ ((m >> 1) & 7)) << 4);
  }
#pragma unroll
  for (int nf = 0; nf < NF; ++nf) {
    const int n = wn * NSPAN + nf * 16 + rr;
    boff[nf] = (n >> 1) * 128 + (((((n & 1) << 2) | gg) ^ ((n >> 1) & 7)) << 4);
  }

  f32x4 acc[MF][NF] = {};
  short8 X0[MH], X1[MH], Y0[MH], Y1[MH];
  short8 Bc0[NF], Bc1[NF];

  auto RD_A = [&](int tt, short8* d, int h) {
    const char* Ab = AsL + (tt & 3) * ABUF;
#pragma unroll
    for (int i = 0; i < MH; ++i) d[i] = *(const short8*)(Ab + aoff[h * MH + i]);
  };
  auto RD_B = [&](int tt, short8* d) {
    const char* Bb = BsL + (tt & 3) * BBUF;
#pragma unroll
    for (int nf = 0; nf < NF; ++nf) d[nf] = *(const short8*)(Bb + boff[nf]);
  };
  auto MFMA_H = [&](short8* a, short8* bfr, int h) {
#pragma unroll
    for (int mi = 0; mi < MH; ++mi)
#pragma unroll
      for (int nf = 0; nf < NF; ++nf)
        acc[h + mi][nf] = __builtin_amdgcn_mfma_f32_16x16x32_bf16(
            a[mi], bfr[nf], acc[h + mi][nf], 0, 0, 0);
  };

#define GITER(T, cA0, cA1, cB, nA0, nA1, nB, STG, VN)                \
  do {                                                               \
    if constexpr (MODE == 1) RD_B((T), Bc0);                         \
    RD_A((T) + 1, nA0, 0);                                           \
    if constexpr (MODE == 0) RD_B((T) + 1, nB);                      \
    __builtin_amdgcn_sched_barrier(0);                               \
    __builtin_amdgcn_s_setprio(1);                                   \
    MFMA_H(cA0, (MODE == 1) ? Bc0 : cB, 0);                          \
    __builtin_amdgcn_s_setprio(0);                                   \
    RD_A((T) + 1, nA1, 1);                                           \
    if (STG) { STAGE_A((T) + 3); STAGE_B((T) + 3); }                 \
    __builtin_amdgcn_sched_barrier(0);                               \
    __builtin_amdgcn_s_setprio(1);                                   \
    MFMA_H(cA1, (MODE == 1) ? Bc0 : cB, MH);                         \
    __builtin_amdgcn_s_setprio(0);                                   \
    VMW(VN);                                                         \
    __builtin_amdgcn_s_barrier();                                    \
    __builtin_amdgcn_sched_barrier(0);                               \
  } while (0)

  STAGE_A(0); STAGE_B(0);
  STAGE_A(1); STAGE_B(1);
  STAGE_A(2); STAGE_B(2);
  VMW(4);
  __builtin_amdgcn_s_barrier();
  __builtin_amdgcn_sched_barrier(0);
  RD_A(0, X0, 0);
  RD_A(0, X1, 1);
  if constexpr (MODE == 0) RD_B(0, Bc0);

  for (int tp = 0; tp < 62; ++tp) {      // T = 0..123
    const int T = 2 * tp;
    GITER(T, X0, X1, Bc0, Y0, Y1, Bc1, true, 4);
    GITER(T + 1, Y0, Y1, Bc1, X0, X1, Bc0, true, 4);
  }
  GITER(124, X0, X1, Bc0, Y0, Y1, Bc1, true, 4);    // stages tile 127
  GITER(125, Y0, Y1, Bc1, X0, X1, Bc0, false, 0);   // drain: 127 landed
  GITER(126, X0, X1, Bc0, Y0, Y1, Bc1, false, 0);   // reads tile 127
  if constexpr (MODE == 1) RD_B(127, Bc0);
  __builtin_amdgcn_s_setprio(1);
  MFMA_H(Y0, (MODE == 1) ? Bc0 : Bc1, 0);
  MFMA_H(Y1, (MODE == 1) ? Bc0 : Bc1, MH);
  __builtin_amdgcn_s_setprio(0);
#undef GITER

  if constexpr (MODE == 1) {
#pragma unroll
    for (int mf = 0; mf < MF; ++mf) {
      const int mbase = m0 + wm * MSPAN + mf * 16 + gg * 4;
#pragma unroll
      for (int nf = 0; nf < NF; ++nf) {
        const int n = n0 + wn * NSPAN + nf * 16 + rr;
#pragma unroll
        for (int j = 0; j < 4; ++j)
          oC[(size_t)(mbase + j) * 4096 + n] = acc[mf][nf][j];
      }
    }
  } else {
    const int b = m0 >> 11;
#pragma unroll
    for (int mf = 0; mf < MF; ++mf) {
      const int mbase = m0 + wm * MSPAN + mf * 16 + gg * 4;
      const int s0 = mbase & 2047;
#pragma unroll
      for (int nf = 0; nf < NF; ++nf) {
        const int n = n0 + wn * NSPAN + nf * 16 + rr;   // region uniform per frag
        if (n < 5120) {  // Q or K: rope
          const int d = n & 127, ii = d >> 1;
          const float sgn = (n & 1) ? 1.0f : -1.0f;
          const float qsc = (n < 4096) ? 0.12752364599362f : 1.0f;  // log2e/sqrt(128)
          ushort res[4];
#pragma unroll
          for (int j = 0; j < 4; ++j) {
            const float2 cs = ((const float2*)fcis)[(size_t)(s0 + j) * 64 + ii];
            float v = acc[mf][nf][j];
            float pv = __shfl_xor(v, 1);
            res[j] = f2bf(qsc * (v * cs.x + sgn * pv * cs.y));
          }
          if (n < 4096) {
            ushort* dst = oQ + ((size_t)(b * 32 + (n >> 7)) * 2048 + s0) * 128 + d;
#pragma unroll
            for (int j = 0; j < 4; ++j) dst[j * 128] = res[j];
          } else {
            ushort* dst =
                oK + ((size_t)(b * 8 + ((n - 4096) >> 7)) * 2048 + s0) * 128 + d;
#pragma unroll
            for (int j = 0; j < 4; ++j) dst[j * 128] = res[j];
          }
        } else {  // V: write V^T [b][hkv][d][s]
          const int n2 = n - 5120;
          ushort4 pk;
          pk.x = f2bf(acc[mf][nf][0]);
          pk.y = f2bf(acc[mf][nf][1]);
          pk.z = f2bf(acc[mf][nf][2]);
          pk.w = f2bf(acc[mf][nf][3]);
          *(ushort4*)&oV[((size_t)(b * 8 + (n2 >> 7)) * 128 + (n2 & 127)) * 2048 + s0] =
              pk;
        }
      }
    }
  }
}

// ------------------------------------------------------------ flash attention
// R9 structure with staging moved to global_load_lds (Common-mistake #1 fix):
// linear LDS dest, inverse-swizzled per-lane global source (rule 21). K tile:
// byte p -> r=p>>8, s=(p>>4)&15, src=K[r][(s^(r&15))*8]. V tile: R=p>>8,
// si=s^(R&15), d=(R>>4)*32+2(R&15)+(si>>3), k=((si>>1)&3)*16+(si&1)*8 —
// both verified against the proven STORE content map. Stage(t+1) issues at
// iter start; VMW(0)+barrier at iter end waits on DMA a full iteration old
// (>= HBM latency; no R8 drain-trap). Read side byte-identical to R9.
__global__ __launch_bounds__(512, 2) void k_attn(const ushort* __restrict__ Qg,
                                                 const ushort* __restrict__ Kg,
                                                 const ushort* __restrict__ Vt,
                                                 ushort* __restrict__ Og) {
  __shared__ ushort Ks[2][64 * 128];   // 2 x 16KB
  __shared__ ushort Vs[2][64 * 128];   // 2 x 16KB
  __shared__ float sml[8][32];

  const int bh = blockIdx.x, qt = blockIdx.y;   // x=bh so q-tiles share an XCD
  const int b = bh >> 5, h = bh & 31, hk = h >> 2;
  const int t = threadIdx.x, w = t >> 6, lane = t & 63;
  const int ln31 = lane & 31, hi = lane >> 5;
  const int q0 = qt * 256;

  short8 qf[8];
  {
    const size_t qbase = ((size_t)bh * 2048 + q0 + w * 32 + ln31) * 128;
#pragma unroll
    for (int tt = 0; tt < 8; ++tt)
      qf[tt] = *(const short8*)&Qg[qbase + tt * 16 + hi * 8];
  }
  const size_t kgb = (size_t)(b * 8 + hk) * 2048 * 128;
  const size_t vgb = (size_t)(b * 8 + hk) * 128 * 2048;

  // gll16 staging geometry: thread t covers LDS bytes t*16 (+8192 for op 2).
  // K op1: r = t>>4 (0..31), s = t&15; K op2: r += 32.
  const int kr1 = t >> 4, ks1 = t & 15;
  const int kr2 = 32 + kr1;
  const ushort* kq1 = Kg + kgb + (size_t)kr1 * 128 + ((ks1 ^ (kr1 & 15)) << 3);
  const ushort* kq2 = Kg + kgb + (size_t)kr2 * 128 + ((ks1 ^ (kr2 & 15)) << 3);
  // V: R=p>>8, s=(p>>4)&15; si=s^(R&15); d=(R>>4)*32+2*(R&15)+(si>>3);
  //    k=((si>>1)&3)*16+(si&1)*8
  const int vR1 = t >> 4, vR2 = 32 + vR1;
  const int vsi1 = ks1 ^ (vR1 & 15), vsi2 = ks1 ^ (vR2 & 15);
  const ushort* vq1 = Vt + vgb +
      (size_t)((vR1 >> 4) * 32 + 2 * (vR1 & 15) + (vsi1 >> 3)) * 2048 +
      ((vsi1 >> 1) & 3) * 16 + (vsi1 & 1) * 8;
  const ushort* vq2 = Vt + vgb +
      (size_t)((vR2 >> 4) * 32 + 2 * (vR2 & 15) + (vsi2 >> 3)) * 2048 +
      ((vsi2 >> 1) & 3) * 16 + (vsi2 & 1) * 8;
  char* kld = (char*)Ks[0] + w * 1024;   // wave-uniform LDS bases
  char* vld = (char*)Vs[0] + w * 1024;

  auto STAGE = [&](int tile, int buf) {
    const size_t kko = (size_t)tile * 8192;   // K rows advance 64/tile * 128
    const size_t vko = (size_t)tile * 64;     // V k advances 64/tile
    gll16(kq1 + kko, kld + buf * 16384);
    gll16(kq2 + kko, kld + buf * 16384 + 8192);
    gll16(vq1 + vko, vld + buf * 16384);
    gll16(vq2 + vko, vld + buf * 16384 + 8192);
  };

  f32x16 ov[4] = {};
  float m_run = -1e30f, l_run = 0.f;

  const int mk = ln31 & 15;
  const int krb0 = ln31 * 256, krb1 = krb0 + 8192;
  const int vrb = (ln31 >> 1) * 256;
  const int vsp = (ln31 & 1) * 8 + hi;
  const int mv = ln31 >> 1;

  STAGE(0, 0);
  VMW(0);
  __builtin_amdgcn_s_barrier();
  __builtin_amdgcn_sched_barrier(0);

  for (int tile = 0; tile < 32; ++tile) {
    const int cur = tile & 1;
    if (tile < 31) STAGE(tile + 1, cur ^ 1);   // DMA overlaps whole iteration

    const char* Kc = (const char*)Ks[cur];
    f32x16 p0 = {}, p1 = {};
    __builtin_amdgcn_s_setprio(1);
#pragma unroll
    for (int tt = 0; tt < 8; ++tt) {
      const int sl = ((tt * 2 + hi) ^ mk) << 4;
      short8 ka0 = *(const short8*)(Kc + krb0 + sl);
      short8 ka1 = *(const short8*)(Kc + krb1 + sl);
      p0 = __builtin_amdgcn_mfma_f32_32x32x16_bf16(ka0, qf[tt], p0, 0, 0, 0);
      p1 = __builtin_amdgcn_mfma_f32_32x32x16_bf16(ka1, qf[tt], p1, 0, 0, 0);
    }
    __builtin_amdgcn_s_setprio(0);

    const float pmax = xhalf_max(fmaxf(vmax16(p0), vmax16(p1)));
    if (!__all(pmax <= m_run + 8.0f)) {   // T13 defer-max
      const float mnew = fmaxf(m_run, pmax);
      const float al = ex2(m_run - mnew);
      m_run = mnew;
      l_run *= al;
      sml[w][ln31] = al;
      const float4 a0 = *(const float4*)&sml[w][hi * 4];
      const float4 a1 = *(const float4*)&sml[w][8 + hi * 4];
      const float4 a2 = *(const float4*)&sml[w][16 + hi * 4];
      const float4 a3 = *(const float4*)&sml[w][24 + hi * 4];
      const float aa[16] = {a0.x, a0.y, a0.z, a0.w, a1.x, a1.y, a1.z, a1.w,
                            a2.x, a2.y, a2.z, a2.w, a3.x, a3.y, a3.z, a3.w};
#pragma unroll
      for (int i = 0; i < 16; ++i) {
        ov[0][i] *= aa[i]; ov[1][i] *= aa[i];
        ov[2][i] *= aa[i]; ov[3][i] *= aa[i];
      }
    }
#pragma unroll
    for (int i = 0; i < 16; ++i) p0[i] = ex2(p0[i] - m_run);
#pragma unroll
    for (int i = 0; i < 16; ++i) p1[i] = ex2(p1[i] - m_run);
    l_run += xhalf_add(vsum16(p0) + vsum16(p1));

    short8 pa[4];
    pa[0] = mk_frag(cvtpk(p0[0], p0[1]), cvtpk(p0[2], p0[3]),
                    cvtpk(p0[4], p0[5]), cvtpk(p0[6], p0[7]), hi);
    pa[1] = mk_frag(cvtpk(p0[8], p0[9]), cvtpk(p0[10], p0[11]),
                    cvtpk(p0[12], p0[13]), cvtpk(p0[14], p0[15]), hi);
    pa[2] = mk_frag(cvtpk(p1[0], p1[1]), cvtpk(p1[2], p1[3]),
                    cvtpk(p1[4], p1[5]), cvtpk(p1[6], p1[7]), hi);
    pa[3] = mk_frag(cvtpk(p1[8], p1[9]), cvtpk(p1[10], p1[11]),
                    cvtpk(p1[12], p1[13]), cvtpk(p1[14], p1[15]), hi);

    const char* Vc = (const char*)Vs[cur];
    __builtin_amdgcn_s_setprio(1);
#pragma unroll
    for (int db = 0; db < 4; ++db) {
      const int rb = vrb + db * 4096;
#pragma unroll
      for (int ks = 0; ks < 4; ++ks) {
        const int sl = ((vsp + ks * 2) ^ mv) << 4;
        short8 bv = *(const short8*)(Vc + rb + sl);
        ov[db] = __builtin_amdgcn_mfma_f32_32x32x16_bf16(pa[ks], bv, ov[db], 0, 0, 0);
      }
    }
    __builtin_amdgcn_s_setprio(0);

    if (tile < 31) {
      VMW(0);                            // stage issued a full iteration ago
      __builtin_amdgcn_s_barrier();
      __builtin_amdgcn_sched_barrier(0);
    }
  }

  sml[w][ln31] = l_run;
  const float4 l0 = *(const float4*)&sml[w][hi * 4];
  const float4 l1 = *(const float4*)&sml[w][8 + hi * 4];
  const float4 l2 = *(const float4*)&sml[w][16 + hi * 4];
  const float4 l3 = *(const float4*)&sml[w][24 + hi * 4];
  const float inv[16] = {1.f / l0.x, 1.f / l0.y, 1.f / l0.z, 1.f / l0.w,
                         1.f / l1.x, 1.f / l1.y, 1.f / l1.z, 1.f / l1.w,
                         1.f / l2.x, 1.f / l2.y, 1.f / l2.z, 1.f / l2.w,
                         1.f / l3.x, 1.f / l3.y, 1.f / l3.z, 1.f / l3.w};
  const int qb0 = q0 + w * 32 + hi * 4;
#pragma unroll
  for (int rg = 0; rg < 4; ++rg)
#pragma unroll
    for (int j = 0; j < 4; ++j) {
      const int sq = qb0 + rg * 8 + j;
      const size_t orow = ((size_t)(b * 2048 + sq)) * 4096 + h * 128 + ln31;
#pragma unroll
      for (int db = 0; db < 4; ++db)
        Og[orow + db * 32] = f2bf(ov[db][rg * 4 + j] * inv[rg * 4 + j]);
    }
}

// --------------------------------------------------------------------- launch
extern "C" void kernel_launch(void* const* d_in, const int* in_sizes, int n_in,
                              void* d_out, int out_size, void* d_ws, size_t ws_size,
                              hipStream_t stream) {
  const float* x = (const float*)d_in[0];
  // d_in[1] = start_pos (always 0: cache fully overwritten, kv_len = S)
  const float* fcis = (const float*)d_in[2];
  const float* wq = (const float*)d_in[3];
  const float* wk = (const float*)d_in[4];
  const float* wv = (const float*)d_in[5];
  const float* wo = (const float*)d_in[6];
  float* out = (float*)d_out;

  char* ws = (char*)d_ws;
  ushort* xb  = (ushort*)(ws);                // 32MB; reused as woT after GEMM0
  ushort* wsT = (ushort*)(ws + 33554432u);    // 48MB [6144][4096] wq|wk|wv ^T
  ushort* qb  = (ushort*)(ws + 83886080u);    // 32MB  Q rope'd+scaled [b][h][s][d]
  ushort* kb  = (ushort*)(ws + 117440512u);   // 8MB   K rope'd [b][hk][s][d]
  ushort* vbT = (ushort*)(ws + 125829120u);   // 8MB   V^T     [b][hk][d][s]
  ushort* woT = xb;                           // after GEMM0
  ushort* ao  = wsT;                          // after GEMM0

  k_cvt<<<8192, 256, 0, stream>>>(x, xb, 2097152);
  k_tr3<<<dim3(96, 64), 256, 0, stream>>>(wq, wk, wv, wsT);
  k_gemm8<0><<<512, 512, 0, stream>>>(xb, wsT, fcis, qb, kb, vbT, nullptr);
  k_tr<<<dim3(64, 64), 256, 0, stream>>>(wo, woT, 4096, 4096);
  k_attn<<<dim3(64, 8), 512, 0, stream>>>(qb, kb, vbT, ao);
  k_gemm8<1><<<256, 512, 0, stream>>>(ao, woT, nullptr, nullptr, nullptr, nullptr,
                                      out);
}

// Round 14
// 519.816 us; speedup vs baseline: 1.0326x; 1.0326x over previous
//
#include <hip/hip_runtime.h>
#include <stdint.h>

// B=2, S=2048, DIM=4096, NQ=32, NKV=8, HD=128, n_rep=4, start_pos=0 (so the
// caches are fully overwritten: K/V == rope(x@wk), x@wv; cache inputs unused).

typedef __attribute__((ext_vector_type(8))) short short8;
typedef __attribute__((ext_vector_type(4))) float f32x4;
typedef __attribute__((ext_vector_type(16))) float f32x16;

#define DEVFN static __device__ __forceinline__

DEVFN ushort f2bf(float f) {
  uint32_t u = __builtin_bit_cast(uint32_t, f);
  u += 0x7fffu + ((u >> 16) & 1);          // round-to-nearest-even
  return (ushort)(u >> 16);
}

DEVFN void gll16(const void* g, void* l) {  // global -> LDS, 16B/lane
  __builtin_amdgcn_global_load_lds(
      (const __attribute__((address_space(1))) void*)g,
      (__attribute__((address_space(3))) void*)l, 16, 0, 0);
}

DEVFN float xhalf_max(float v) { return fmaxf(v, __shfl_xor(v, 32)); }
DEVFN float xhalf_add(float v) { return v + __shfl_xor(v, 32); }

#if __has_builtin(__builtin_amdgcn_exp2f)
DEVFN float ex2(float x) { return __builtin_amdgcn_exp2f(x); }
#else
DEVFN float ex2(float x) {
  float r;
  asm("v_exp_f32 %0, %1" : "=v"(r) : "v"(x));
  return r;
}
#endif

// packed 2xf32 -> bf16x2, lo=a hi=b (HW-verified operand order, T12/m214v22)
DEVFN uint32_t cvtpk(float a, float b) {
  uint32_t r;
  asm("v_cvt_pk_bf16_f32 %0, %1, %2" : "=v"(r) : "v"(a), "v"(b));
  return r;
}

DEVFN float vmax16(const f32x16& v) {      // max3-fusable tree, depth 3
  float a0 = fmaxf(fmaxf(v[0], v[1]), v[2]);
  float a1 = fmaxf(fmaxf(v[3], v[4]), v[5]);
  float a2 = fmaxf(fmaxf(v[6], v[7]), v[8]);
  float a3 = fmaxf(fmaxf(v[9], v[10]), v[11]);
  float a4 = fmaxf(fmaxf(v[12], v[13]), v[14]);
  float b0 = fmaxf(fmaxf(a0, a1), a2);
  float b1 = fmaxf(fmaxf(a3, a4), v[15]);
  return fmaxf(b0, b1);
}
DEVFN float vsum16(const f32x16& v) {      // pairwise tree, depth 4
  float s0 = (v[0] + v[1]) + (v[2] + v[3]);
  float s1 = (v[4] + v[5]) + (v[6] + v[7]);
  float s2 = (v[8] + v[9]) + (v[10] + v[11]);
  float s3 = (v[12] + v[13]) + (v[14] + v[15]);
  return (s0 + s1) + (s2 + s3);
}

// Build PV A-frag (8 contiguous k per lane) from packed S^T words.
DEVFN short8 mk_frag(uint32_t w0, uint32_t w1, uint32_t w2, uint32_t w3, int hi) {
  uint32_t x0 = __shfl_xor(w0, 32);
  uint32_t x1 = __shfl_xor(w1, 32);
  uint32_t x2 = __shfl_xor(w2, 32);
  uint32_t x3 = __shfl_xor(w3, 32);
  uint4 u;
  u.x = hi ? x2 : w0;
  u.y = hi ? x3 : w1;
  u.z = hi ? w2 : x0;
  u.w = hi ? w3 : x1;
  return __builtin_bit_cast(short8, u);
}

#define VMW(N) asm volatile("s_waitcnt vmcnt(" #N ")" ::: "memory")

// ---------------- transpose + cvt tile body: [R][C]f32 -> [C][R]bf16 (G13)
DEVFN void tr_body(const float* __restrict__ src, ushort* __restrict__ dst,
                   int R, int C, int c0, int r0, int t, ushort* tl) {
  const int r = t >> 4, c4 = (t & 15) << 2;
#pragma unroll
  for (int i = 0; i < 4; ++i) {
    const int rr = r + i * 16;
    float4 v = *(const float4*)&src[(size_t)(r0 + rr) * C + c0 + c4];
    ushort bv[4] = {f2bf(v.x), f2bf(v.y), f2bf(v.z), f2bf(v.w)};
#pragma unroll
    for (int j = 0; j < 4; ++j) {
      const int c = c4 + j;
      *(ushort*)((char*)tl + c * 128 + (((rr >> 3) ^ (c & 7)) << 4) +
                 ((rr & 7) << 1)) = bv[j];
    }
  }
  __syncthreads();
  const int cc = t >> 2;
#pragma unroll
  for (int i = 0; i < 2; ++i) {
    const int ch = (t & 3) + i * 4;        // 8-element r-chunk
    short8 v = *(const short8*)((char*)tl + cc * 128 + ((ch ^ (cc & 7)) << 4));
    *(short8*)&dst[(size_t)(c0 + cc) * R + r0 + ch * 8] = v;
  }
}

// -------------- merged prep: x fp32->bf16 (blocks 0..8191) + wq|wk|wv
// transpose (blocks 8192..14335, flattened 96x64)
__global__ __launch_bounds__(256) void k_prep(const float* __restrict__ x,
                                              ushort* __restrict__ xb,
                                              const float* __restrict__ wq,
                                              const float* __restrict__ wk,
                                              const float* __restrict__ wv,
                                              ushort* __restrict__ wsT) {
  __shared__ ushort tl[64 * 64];
  const int bx = blockIdx.x;
  if (bx < 8192) {
    const int i = bx * 256 + threadIdx.x;
    const float4* s4 = (const float4*)x + (size_t)i * 2;
    float4 a = s4[0], b = s4[1];
    uint4 o;
    o.x = (uint32_t)f2bf(a.x) | ((uint32_t)f2bf(a.y) << 16);
    o.y = (uint32_t)f2bf(a.z) | ((uint32_t)f2bf(a.w) << 16);
    o.z = (uint32_t)f2bf(b.x) | ((uint32_t)f2bf(b.y) << 16);
    o.w = (uint32_t)f2bf(b.z) | ((uint32_t)f2bf(b.w) << 16);
    ((uint4*)xb)[i] = o;
    return;
  }
  const int bq = bx - 8192;                // 0..6143
  const int cx = bq % 96, ry = bq / 96;
  const float* src;
  ushort* d;
  int C, cb;
  if (cx < 64) { src = wq; d = wsT; C = 4096; cb = cx; }
  else if (cx < 80) { src = wk; d = wsT + (size_t)4096 * 4096; C = 1024; cb = cx - 64; }
  else { src = wv; d = wsT + (size_t)5120 * 4096; C = 1024; cb = cx - 80; }
  tr_body(src, d, 4096, C, cb * 64, ry * 64, threadIdx.x, tl);
}

// ------------------------------------- decoupled reg-dbuf pipelined GEMM C=A*B^T
// (R9-proven: ring-4 LDS, per-tile counted VMW(4), reg-double-buffered frags.)
// MODE 0: BN=192, N=6144 (Q|K|V rows 0/4096/5120), 4M x 2N waves, B dbuf,
//         rope epilogue. MODE 1: BN=256, N=4096, 2M x 4N waves, B JIT, f32 C.
template <int MODE>
__global__ __launch_bounds__(512, 2) void k_gemm8(
    const ushort* __restrict__ A, const ushort* __restrict__ Bp,
    const float* __restrict__ fcis, ushort* __restrict__ oQ,
    ushort* __restrict__ oK, ushort* __restrict__ oV, float* __restrict__ oC) {
  constexpr int K = 4096;
  constexpr int BN = MODE ? 256 : 192;
  constexpr int NBX = MODE ? 16 : 32;
  constexpr int ABUF = 16384;            // 256 rows * 64 B
  constexpr int BBUF = BN * 64;          // 16384 / 12288
  constexpr int NT = K / 32;             // 128
  constexpr int WNG = MODE ? 4 : 2;      // wave grid: (8/WNG) x WNG
  constexpr int MF = MODE ? 8 : 4;       // m-frags per wave
  constexpr int NF = MODE ? 4 : 6;       // n-frags per wave
  constexpr int MH = MF / 2;
  constexpr int MSPAN = 16 * MF;         // 128 / 64
  constexpr int NSPAN = 16 * NF;         // 64 / 96

  __shared__ char smem[4 * ABUF + 4 * BBUF];   // 128 / 112 KB
  char* AsL = smem;
  char* BsL = smem + 4 * ABUF;

  constexpr int nwg = NBX * 16;
  const int bid = blockIdx.x;
  const int wg = (bid & 7) * (nwg >> 3) + (bid >> 3);   // XCD swizzle (bijective)
  const int nb = wg % NBX, mb = wg / NBX;
  const int m0 = mb * 256, n0 = nb * BN;

  const int tid = threadIdx.x;
  const int w = tid >> 6, lane = tid & 63;
  const int gg = lane >> 4, rr = lane & 15;
  const int wm = w / WNG, wn = w % WNG;

  // staging: linear LDS dest (gll16), inverse-swizzled global source.
  const int l8 = lane >> 3, s7 = lane & 7;
  const int Ra0 = w * 8 + l8, Ra1 = 64 + Ra0;
  const int ea0 = s7 ^ (Ra0 & 7), ea1 = s7 ^ (Ra1 & 7);
  const ushort* agp0 = A + (size_t)(m0 + 2 * Ra0 + (ea0 >> 2)) * K + (ea0 & 3) * 8;
  const ushort* agp1 = A + (size_t)(m0 + 2 * Ra1 + (ea1 >> 2)) * K + (ea1 & 3) * 8;
  char* lda0 = AsL + w * 1024;
  char* lda1 = AsL + 8192 + w * 1024;

  const int Rb0 = w * 8 + l8;
  const int eb0 = s7 ^ (Rb0 & 7);
  const ushort* bgp0 = Bp + (size_t)(n0 + 2 * Rb0 + (eb0 >> 2)) * K + (eb0 & 3) * 8;
  char* ldb0 = BsL + w * 1024;
  const int Rb1 = MODE ? (64 + w * 8 + l8) : (64 + w * 4 + l8);
  const int eb1 = s7 ^ (Rb1 & 7);
  const ushort* bgp1 = Bp + (size_t)(n0 + 2 * Rb1 + (eb1 >> 2)) * K + (eb1 & 3) * 8;
  char* ldb1 = BsL + 8192 + (MODE ? w * 1024 : w * 512);

  auto STAGE_A = [&](int t) {
    const int bo = t & 3;
    const size_t ko = (size_t)t * 32;
    gll16(agp0 + ko, lda0 + bo * ABUF);
    gll16(agp1 + ko, lda1 + bo * ABUF);
  };
  auto STAGE_B = [&](int t) {
    const int bo = t & 3;
    const size_t ko = (size_t)t * 32;
    gll16(bgp0 + ko, ldb0 + bo * BBUF);
    if constexpr (MODE) {
      gll16(bgp1 + ko, ldb1 + bo * BBUF);
    } else {
      if (lane < 32) gll16(bgp1 + ko, ldb1 + bo * BBUF);
    }
  };

  int aoff[MF], boff[NF];
#pragma unroll
  for (int mf = 0; mf < MF; ++mf) {
    const int m = wm * MSPAN + mf * 16 + rr;
    aoff[mf] = (m >> 1) * 128 + (((((m & 1) << 2) | gg) ^ ((m >> 1) & 7)) << 4);
  }
#pragma unroll
  for (int nf = 0; nf < NF; ++nf) {
    const int n = wn * NSPAN + nf * 16 + rr;
    boff[nf] = (n >> 1) * 128 + (((((n & 1) << 2) | gg) ^ ((n >> 1) & 7)) << 4);
  }

  f32x4 acc[MF][NF] = {};
  short8 X0[MH], X1[MH], Y0[MH], Y1[MH];
  short8 Bc0[NF], Bc1[NF];

  auto RD_A = [&](int tt, short8* d, int h) {
    const char* Ab = AsL + (tt & 3) * ABUF;
#pragma unroll
    for (int i = 0; i < MH; ++i) d[i] = *(const short8*)(Ab + aoff[h * MH + i]);
  };
  auto RD_B = [&](int tt, short8* d) {
    const char* Bb = BsL + (tt & 3) * BBUF;
#pragma unroll
    for (int nf = 0; nf < NF; ++nf) d[nf] = *(const short8*)(Bb + boff[nf]);
  };
  auto MFMA_H = [&](short8* a, short8* bfr, int h) {
#pragma unroll
    for (int mi = 0; mi < MH; ++mi)
#pragma unroll
      for (int nf = 0; nf < NF; ++nf)
        acc[h + mi][nf] = __builtin_amdgcn_mfma_f32_16x16x32_bf16(
            a[mi], bfr[nf], acc[h + mi][nf], 0, 0, 0);
  };

#define GITER(T, cA0, cA1, cB, nA0, nA1, nB, STG, VN)                \
  do {                                                               \
    if constexpr (MODE == 1) RD_B((T), Bc0);                         \
    RD_A((T) + 1, nA0, 0);                                           \
    if constexpr (MODE == 0) RD_B((T) + 1, nB);                      \
    __builtin_amdgcn_sched_barrier(0);                               \
    __builtin_amdgcn_s_setprio(1);                                   \
    MFMA_H(cA0, (MODE == 1) ? Bc0 : cB, 0);                          \
    __builtin_amdgcn_s_setprio(0);                                   \
    RD_A((T) + 1, nA1, 1);                                           \
    if (STG) { STAGE_A((T) + 3); STAGE_B((T) + 3); }                 \
    __builtin_amdgcn_sched_barrier(0);                               \
    __builtin_amdgcn_s_setprio(1);                                   \
    MFMA_H(cA1, (MODE == 1) ? Bc0 : cB, MH);                         \
    __builtin_amdgcn_s_setprio(0);                                   \
    VMW(VN);                                                         \
    __builtin_amdgcn_s_barrier();                                    \
    __builtin_amdgcn_sched_barrier(0);                               \
  } while (0)

  STAGE_A(0); STAGE_B(0);
  STAGE_A(1); STAGE_B(1);
  STAGE_A(2); STAGE_B(2);
  VMW(4);
  __builtin_amdgcn_s_barrier();
  __builtin_amdgcn_sched_barrier(0);
  RD_A(0, X0, 0);
  RD_A(0, X1, 1);
  if constexpr (MODE == 0) RD_B(0, Bc0);

  for (int tp = 0; tp < 62; ++tp) {      // T = 0..123
    const int T = 2 * tp;
    GITER(T, X0, X1, Bc0, Y0, Y1, Bc1, true, 4);
    GITER(T + 1, Y0, Y1, Bc1, X0, X1, Bc0, true, 4);
  }
  GITER(124, X0, X1, Bc0, Y0, Y1, Bc1, true, 4);    // stages tile 127
  GITER(125, Y0, Y1, Bc1, X0, X1, Bc0, false, 0);   // drain: 127 landed
  GITER(126, X0, X1, Bc0, Y0, Y1, Bc1, false, 0);   // reads tile 127
  if constexpr (MODE == 1) RD_B(127, Bc0);
  __builtin_amdgcn_s_setprio(1);
  MFMA_H(Y0, (MODE == 1) ? Bc0 : Bc1, 0);
  MFMA_H(Y1, (MODE == 1) ? Bc0 : Bc1, MH);
  __builtin_amdgcn_s_setprio(0);
#undef GITER

  if constexpr (MODE == 1) {
#pragma unroll
    for (int mf = 0; mf < MF; ++mf) {
      const int mbase = m0 + wm * MSPAN + mf * 16 + gg * 4;
#pragma unroll
      for (int nf = 0; nf < NF; ++nf) {
        const int n = n0 + wn * NSPAN + nf * 16 + rr;
#pragma unroll
        for (int j = 0; j < 4; ++j)
          oC[(size_t)(mbase + j) * 4096 + n] = acc[mf][nf][j];
      }
    }
  } else {
    const int b = m0 >> 11;
#pragma unroll
    for (int mf = 0; mf < MF; ++mf) {
      const int mbase = m0 + wm * MSPAN + mf * 16 + gg * 4;
      const int s0 = mbase & 2047;
#pragma unroll
      for (int nf = 0; nf < NF; ++nf) {
        const int n = n0 + wn * NSPAN + nf * 16 + rr;   // region uniform per frag
        if (n < 5120) {  // Q or K: rope
          const int d = n & 127, ii = d >> 1;
          const float sgn = (n & 1) ? 1.0f : -1.0f;
          const float qsc = (n < 4096) ? 0.12752364599362f : 1.0f;  // log2e/sqrt(128)
          ushort res[4];
#pragma unroll
          for (int j = 0; j < 4; ++j) {
            const float2 cs = ((const float2*)fcis)[(size_t)(s0 + j) * 64 + ii];
            float v = acc[mf][nf][j];
            float pv = __shfl_xor(v, 1);
            res[j] = f2bf(qsc * (v * cs.x + sgn * pv * cs.y));
          }
          if (n < 4096) {
            ushort* dst = oQ + ((size_t)(b * 32 + (n >> 7)) * 2048 + s0) * 128 + d;
#pragma unroll
            for (int j = 0; j < 4; ++j) dst[j * 128] = res[j];
          } else {
            ushort* dst =
                oK + ((size_t)(b * 8 + ((n - 4096) >> 7)) * 2048 + s0) * 128 + d;
#pragma unroll
            for (int j = 0; j < 4; ++j) dst[j * 128] = res[j];
          }
        } else {  // V: write V^T [b][hkv][d][s]
          const int n2 = n - 5120;
          ushort4 pk;
          pk.x = f2bf(acc[mf][nf][0]);
          pk.y = f2bf(acc[mf][nf][1]);
          pk.z = f2bf(acc[mf][nf][2]);
          pk.w = f2bf(acc[mf][nf][3]);
          *(ushort4*)&oV[((size_t)(b * 8 + (n2 >> 7)) * 128 + (n2 & 127)) * 2048 + s0] =
              pk;
        }
      }
    }
  }
}

// ----------------------- flash attention (R12-proven) + fused wo-transpose
// Blocks 0..511: attn (bh=bid&63, qt=bid>>6), byte-identical R12 body with
// Ks/Vs/sml overlaid on one shared block. Blocks 512..2559: wo transpose,
// 2 tiles per 512-thread block (two 256-thread halves, 16KB of shared) —
// pure-BW work co-scheduled under attn's compute. Disjoint outputs; no
// inter-block ordering assumed.
__global__ __launch_bounds__(512, 2) void k_attn_tr(const ushort* __restrict__ Qg,
                                                    const ushort* __restrict__ Kg,
                                                    const ushort* __restrict__ Vt,
                                                    ushort* __restrict__ Og,
                                                    const float* __restrict__ wo,
                                                    ushort* __restrict__ woT) {
  __shared__ char shmem[66560];   // attn: Ks 32K | Vs 32K | sml 1K; tr: 2x8K

  const int bid = blockIdx.x;
  if (bid >= 512) {               // ---- wo transpose part
    const int t2 = bid - 512;     // 0..2047
    const int half = threadIdx.x >> 8;
    const int t = threadIdx.x & 255;
    const int idx = t2 * 2 + half;            // 0..4095 -> 64x64 tiles
    ushort* tl = (ushort*)(shmem + half * 8192);
    tr_body(wo, woT, 4096, 4096, (idx & 63) * 64, (idx >> 6) * 64, t, tl);
    return;
  }

  // ---- attention part
  const int bh = bid & 63, qt = bid >> 6;
  const int b = bh >> 5, h = bh & 31, hk = h >> 2;
  const int t = threadIdx.x, w = t >> 6, lane = t & 63;
  const int ln31 = lane & 31, hi = lane >> 5;
  const int q0 = qt * 256;
  float (*sml)[32] = (float(*)[32])(shmem + 65536);

  short8 qf[8];
  {
    const size_t qbase = ((size_t)bh * 2048 + q0 + w * 32 + ln31) * 128;
#pragma unroll
    for (int tt = 0; tt < 8; ++tt)
      qf[tt] = *(const short8*)&Qg[qbase + tt * 16 + hi * 8];
  }
  const size_t kgb = (size_t)(b * 8 + hk) * 2048 * 128;
  const size_t vgb = (size_t)(b * 8 + hk) * 128 * 2048;

  const int srow = t >> 3;               // 0..63
  const int ssl = (t & 7) * 2;           // even 16B slot
  const int s0 = ssl ^ (srow & 15);      // swizzled slot (pair partner = s0^1)
  const int vd = 2 * (t >> 3) + ((t & 7) >> 2);
  const int vkl = (t & 3) * 16;
  const ushort* kgp = Kg + kgb + (size_t)srow * 128 + ssl * 8;
  const ushort* vgp = Vt + vgb + (size_t)vd * 2048 + vkl;

  uint4 rk0, rk1, rv0, rv1;
  auto LOAD = [&](int k0) {
    const uint4* kp = (const uint4*)(kgp + (size_t)k0 * 128);
    rk0 = kp[0];
    rk1 = kp[1];
    const uint4* vp = (const uint4*)(vgp + k0);
    rv0 = vp[0];
    rv1 = vp[1];
  };
  auto STORE = [&](int buf) {
    char* kd = shmem + buf * 16384 + srow * 256;
    *(uint4*)(kd + (s0 << 4)) = rk0;
    *(uint4*)(kd + ((s0 ^ 1) << 4)) = rk1;
    char* vdd = shmem + 32768 + buf * 16384 + srow * 256;
    *(uint4*)(vdd + (s0 << 4)) = rv0;
    *(uint4*)(vdd + ((s0 ^ 1) << 4)) = rv1;
  };

  f32x16 ov[4] = {};
  float m_run = -1e30f, l_run = 0.f;

  const int mk = ln31 & 15;
  const int krb0 = ln31 * 256, krb1 = krb0 + 8192;
  const int vrb = (ln31 >> 1) * 256;
  const int vsp = (ln31 & 1) * 8 + hi;
  const int mv = ln31 >> 1;

  LOAD(0);
  STORE(0);
  __syncthreads();

  for (int tile = 0; tile < 32; ++tile) {
    const int cur = tile & 1;
    if (tile < 31) LOAD((tile + 1) * 64);

    const char* Kc = shmem + cur * 16384;
    f32x16 p0 = {}, p1 = {};
    __builtin_amdgcn_s_setprio(1);
#pragma unroll
    for (int tt = 0; tt < 8; ++tt) {
      const int sl = ((tt * 2 + hi) ^ mk) << 4;
      short8 ka0 = *(const short8*)(Kc + krb0 + sl);
      short8 ka1 = *(const short8*)(Kc + krb1 + sl);
      p0 = __builtin_amdgcn_mfma_f32_32x32x16_bf16(ka0, qf[tt], p0, 0, 0, 0);
      p1 = __builtin_amdgcn_mfma_f32_32x32x16_bf16(ka1, qf[tt], p1, 0, 0, 0);
    }
    __builtin_amdgcn_s_setprio(0);

    const float pmax = xhalf_max(fmaxf(vmax16(p0), vmax16(p1)));
    if (!__all(pmax <= m_run + 8.0f)) {   // T13 defer-max
      const float mnew = fmaxf(m_run, pmax);
      const float al = ex2(m_run - mnew);
      m_run = mnew;
      l_run *= al;
      sml[w][ln31] = al;
      const float4 a0 = *(const float4*)&sml[w][hi * 4];
      const float4 a1 = *(const float4*)&sml[w][8 + hi * 4];
      const float4 a2 = *(const float4*)&sml[w][16 + hi * 4];
      const float4 a3 = *(const float4*)&sml[w][24 + hi * 4];
      const float aa[16] = {a0.x, a0.y, a0.z, a0.w, a1.x, a1.y, a1.z, a1.w,
                            a2.x, a2.y, a2.z, a2.w, a3.x, a3.y, a3.z, a3.w};
#pragma unroll
      for (int i = 0; i < 16; ++i) {
        ov[0][i] *= aa[i]; ov[1][i] *= aa[i];
        ov[2][i] *= aa[i]; ov[3][i] *= aa[i];
      }
    }
#pragma unroll
    for (int i = 0; i < 16; ++i) p0[i] = ex2(p0[i] - m_run);
#pragma unroll
    for (int i = 0; i < 16; ++i) p1[i] = ex2(p1[i] - m_run);
    l_run += xhalf_add(vsum16(p0) + vsum16(p1));

    short8 pa[4];
    pa[0] = mk_frag(cvtpk(p0[0], p0[1]), cvtpk(p0[2], p0[3]),
                    cvtpk(p0[4], p0[5]), cvtpk(p0[6], p0[7]), hi);
    pa[1] = mk_frag(cvtpk(p0[8], p0[9]), cvtpk(p0[10], p0[11]),
                    cvtpk(p0[12], p0[13]), cvtpk(p0[14], p0[15]), hi);
    pa[2] = mk_frag(cvtpk(p1[0], p1[1]), cvtpk(p1[2], p1[3]),
                    cvtpk(p1[4], p1[5]), cvtpk(p1[6], p1[7]), hi);
    pa[3] = mk_frag(cvtpk(p1[8], p1[9]), cvtpk(p1[10], p1[11]),
                    cvtpk(p1[12], p1[13]), cvtpk(p1[14], p1[15]), hi);

    const char* Vc = shmem + 32768 + cur * 16384;
    __builtin_amdgcn_s_setprio(1);
#pragma unroll
    for (int db = 0; db < 4; ++db) {
      const int rb = vrb + db * 4096;
#pragma unroll
      for (int ks = 0; ks < 4; ++ks) {
        const int sl = ((vsp + ks * 2) ^ mv) << 4;
        short8 bv = *(const short8*)(Vc + rb + sl);
        ov[db] = __builtin_amdgcn_mfma_f32_32x32x16_bf16(pa[ks], bv, ov[db], 0, 0, 0);
      }
    }
    __builtin_amdgcn_s_setprio(0);

    if (tile < 31) STORE(cur ^ 1);
    __syncthreads();
  }

  sml[w][ln31] = l_run;
  const float4 l0 = *(const float4*)&sml[w][hi * 4];
  const float4 l1 = *(const float4*)&sml[w][8 + hi * 4];
  const float4 l2 = *(const float4*)&sml[w][16 + hi * 4];
  const float4 l3 = *(const float4*)&sml[w][24 + hi * 4];
  const float inv[16] = {1.f / l0.x, 1.f / l0.y, 1.f / l0.z, 1.f / l0.w,
                         1.f / l1.x, 1.f / l1.y, 1.f / l1.z, 1.f / l1.w,
                         1.f / l2.x, 1.f / l2.y, 1.f / l2.z, 1.f / l2.w,
                         1.f / l3.x, 1.f / l3.y, 1.f / l3.z, 1.f / l3.w};
  const int qb0 = q0 + w * 32 + hi * 4;
#pragma unroll
  for (int rg = 0; rg < 4; ++rg)
#pragma unroll
    for (int j = 0; j < 4; ++j) {
      const int sq = qb0 + rg * 8 + j;
      const size_t orow = ((size_t)(b * 2048 + sq)) * 4096 + h * 128 + ln31;
#pragma unroll
      for (int db = 0; db < 4; ++db)
        Og[orow + db * 32] = f2bf(ov[db][rg * 4 + j] * inv[rg * 4 + j]);
    }
}

// --------------------------------------------------------------------- launch
extern "C" void kernel_launch(void* const* d_in, const int* in_sizes, int n_in,
                              void* d_out, int out_size, void* d_ws, size_t ws_size,
                              hipStream_t stream) {
  const float* x = (const float*)d_in[0];
  // d_in[1] = start_pos (always 0: cache fully overwritten, kv_len = S)
  const float* fcis = (const float*)d_in[2];
  const float* wq = (const float*)d_in[3];
  const float* wk = (const float*)d_in[4];
  const float* wv = (const float*)d_in[5];
  const float* wo = (const float*)d_in[6];
  float* out = (float*)d_out;

  char* ws = (char*)d_ws;
  ushort* xb  = (ushort*)(ws);                // 32MB; reused as woT after GEMM0
  ushort* wsT = (ushort*)(ws + 33554432u);    // 48MB [6144][4096] wq|wk|wv ^T
  ushort* qb  = (ushort*)(ws + 83886080u);    // 32MB  Q rope'd+scaled [b][h][s][d]
  ushort* kb  = (ushort*)(ws + 117440512u);   // 8MB   K rope'd [b][hk][s][d]
  ushort* vbT = (ushort*)(ws + 125829120u);   // 8MB   V^T     [b][hk][d][s]
  ushort* woT = xb;                           // after GEMM0
  ushort* ao  = wsT;                          // after GEMM0

  k_prep<<<14336, 256, 0, stream>>>(x, xb, wq, wk, wv, wsT);
  k_gemm8<0><<<512, 512, 0, stream>>>(xb, wsT, fcis, qb, kb, vbT, nullptr);
  k_attn_tr<<<2560, 512, 0, stream>>>(qb, kb, vbT, ao, wo, woT);
  k_gemm8<1><<<256, 512, 0, stream>>>(ao, woT, nullptr, nullptr, nullptr, nullptr,
                                      out);
}